// Round 8
// baseline (211.890 us; speedup 1.0000x reference)
//
#include <hip/hip_runtime.h>
#include <cstdint>
#include <cstddef>

// Problem constants (fixed by the reference file)
#define NB   8
#define VV   4096
#define KNN  40
#define NTOT 32768
#define CAP  224   // compact within-radius list capacity per query
#define INFB 0x7F800000u
#define ONEB 0x3F800000u

__device__ __forceinline__ int xbucket(float x) {
  int b = (int)floorf((x + 4.f) * 32.f);
  return b < 0 ? 0 : (b > 255 ? 255 : b);
}

// ---------------------------------------------------------------------------
// Kernel 1: coords = x@W_sp + b_sp ; feat = x@W_prop + b_prop ;
//           xW = x @ W_out[128:192,:]  (written into d_out, fused later)
// ---------------------------------------------------------------------------
__global__ __launch_bounds__(256) void k_prep(
    const float* __restrict__ x, const float* __restrict__ W_prop,
    const float* __restrict__ b_prop, const float* __restrict__ W_sp,
    const float* __restrict__ b_sp, const float* __restrict__ W_out,
    float* __restrict__ coords, float* __restrict__ feat,
    float* __restrict__ xW)
{
  __shared__ float xt[64][64];
  const int t = threadIdx.x;
  const int row0 = blockIdx.x * 64;

  #pragma unroll
  for (int i = 0; i < 16; ++i) {
    int idx = t + i * 256;
    xt[idx >> 6][idx & 63] = x[(size_t)row0 * 64 + idx];
  }
  __syncthreads();

  {
    const int col = t & 63, rb = (t >> 6) * 16;
    float acc[16];
    #pragma unroll
    for (int i = 0; i < 16; ++i) acc[i] = b_prop[col];
    for (int k = 0; k < 64; k += 4) {
      const float w0 = W_prop[(k + 0) * 64 + col];
      const float w1 = W_prop[(k + 1) * 64 + col];
      const float w2 = W_prop[(k + 2) * 64 + col];
      const float w3 = W_prop[(k + 3) * 64 + col];
      #pragma unroll
      for (int i = 0; i < 16; ++i) {
        const float4 a4 = *(const float4*)&xt[rb + i][k];
        acc[i] += a4.x * w0 + a4.y * w1 + a4.z * w2 + a4.w * w3;
      }
    }
    #pragma unroll
    for (int i = 0; i < 16; ++i)
      feat[(size_t)(row0 + rb + i) * 64 + col] = acc[i];
  }

  {
    const int col = t & 127, who = t >> 7;
    #pragma unroll
    for (int p = 0; p < 2; ++p) {
      const int rb = who * 16 + p * 32;
      float acc[16];
      #pragma unroll
      for (int i = 0; i < 16; ++i) acc[i] = 0.f;
      for (int k = 0; k < 64; k += 4) {
        const float w0 = W_out[(size_t)(128 + k + 0) * 128 + col];
        const float w1 = W_out[(size_t)(128 + k + 1) * 128 + col];
        const float w2 = W_out[(size_t)(128 + k + 2) * 128 + col];
        const float w3 = W_out[(size_t)(128 + k + 3) * 128 + col];
        #pragma unroll
        for (int i = 0; i < 16; ++i) {
          const float4 a4 = *(const float4*)&xt[rb + i][k];
          acc[i] += a4.x * w0 + a4.y * w1 + a4.z * w2 + a4.w * w3;
        }
      }
      #pragma unroll
      for (int i = 0; i < 16; ++i)
        xW[(size_t)(row0 + rb + i) * 128 + col] = acc[i];
    }
  }

  if (t < 64) {
    float a0 = b_sp[0], a1 = b_sp[1], a2 = b_sp[2], a3 = b_sp[3];
    for (int k = 0; k < 64; ++k) {
      const float xv = xt[t][k];
      a0 += xv * W_sp[k * 4 + 0];
      a1 += xv * W_sp[k * 4 + 1];
      a2 += xv * W_sp[k * 4 + 2];
      a3 += xv * W_sp[k * 4 + 3];
    }
    ((float4*)coords)[row0 + t] = make_float4(a0, a1, a2, a3);
  }
}

// ---------------------------------------------------------------------------
// Kernel 1b: per-event counting sort of coords by x (in place), 256 buckets.
// Emits perm (sorted pos -> original local idx, u16) and bucket prefix (u16).
// One block per event.
// ---------------------------------------------------------------------------
__global__ __launch_bounds__(512) void k_sort(
    float* __restrict__ coords, unsigned short* __restrict__ perm,
    unsigned short* __restrict__ prefg)
{
  __shared__ float4 cs[VV];      // 64 KB staging (makes in-place safe)
  __shared__ int hist[256];
  __shared__ int pref[257];
  const int t = threadIdx.x, ev = blockIdx.x;
  const int evbase = ev * VV;
  float4* cg = (float4*)coords + evbase;

  for (int i = t; i < VV; i += 512) cs[i] = cg[i];
  if (t < 256) hist[t] = 0;
  __syncthreads();

  for (int i = t; i < VV; i += 512)
    atomicAdd(&hist[xbucket(cs[i].x)], 1);
  __syncthreads();

  if (t < 64) {
    const int l = t;
    const int h0 = hist[4*l], h1 = hist[4*l+1], h2 = hist[4*l+2], h3 = hist[4*l+3];
    const int s = h0 + h1 + h2 + h3;
    int incl = s;
    #pragma unroll
    for (int off = 1; off < 64; off <<= 1) {
      const int v = __shfl_up(incl, off);
      if (l >= off) incl += v;
    }
    const int excl = incl - s;
    pref[4*l]   = excl;
    pref[4*l+1] = excl + h0;
    pref[4*l+2] = excl + h0 + h1;
    pref[4*l+3] = excl + h0 + h1 + h2;
    if (l == 63) pref[256] = excl + s;   // == VV
  }
  __syncthreads();
  if (t < 256) hist[t] = 0;              // reuse as scatter counters
  __syncthreads();

  for (int i = t; i < VV; i += 512) {
    const int b = xbucket(cs[i].x);
    const int pos = pref[b] + atomicAdd(&hist[b], 1);
    cg[pos] = cs[i];
    perm[evbase + pos] = (unsigned short)i;
  }
  if (t < 257) prefg[ev * 257 + t] = (unsigned short)pref[t];
}

// ---------------------------------------------------------------------------
// Kernel 2: per-query KNN + weighted max/mean aggregation on SORTED coords.
// Window prune: only candidates with |c.x - q.x| <= ~1 (bucket window) are
// scanned (~52% of pairs eliminated). 512 thr / 8 waves / 2 blocks/CU.
// ---------------------------------------------------------------------------
template <int NC>
__device__ __forceinline__ unsigned bs40(const uint2* __restrict__ list,
                                         int M, int lane) {
  unsigned dv[NC];
  #pragma unroll
  for (int j = 0; j < NC; ++j) {
    const int e = lane + j * 64;
    dv[j] = (e < M) ? list[e].x : INFB;
  }
  unsigned lo = 0, hi = ONEB;
  while (lo < hi) {
    const unsigned mid = (lo + hi) >> 1;
    int cnt = 0;
    #pragma unroll
    for (int j = 0; j < NC; ++j)
      cnt += (int)__popcll(__ballot(dv[j] <= mid));
    if (cnt >= KNN) hi = mid; else lo = mid + 1;
  }
  return hi;
}

#define AGG_CHUNK(J0, N)                                                     \
  {                                                                          \
    float fv[N], wgt[N];                                                     \
    _Pragma("unroll")                                                        \
    for (int j = 0; j < N; ++j) {                                            \
      const uint2 en = list[(J0) + j];                                       \
      wgt[j] = __expf(-10.f * __uint_as_float(en.x));                        \
      const int ei = __builtin_amdgcn_readfirstlane((int)en.y);              \
      fv[j] = fe[(size_t)ei * 64 + lane];                                    \
    }                                                                        \
    _Pragma("unroll")                                                        \
    for (int j = 0; j < N; ++j) {                                            \
      const float v = fv[j] * wgt[j];                                        \
      vmax = fmaxf(vmax, v);                                                 \
      vsum += v;                                                             \
    }                                                                        \
  }

__global__ __launch_bounds__(512, 4) void k_knn(
    const float* __restrict__ coords,           // sorted by x per event
    const unsigned short* __restrict__ perm,    // sorted pos -> orig local
    const unsigned short* __restrict__ prefg,
    const float* __restrict__ feat, float* __restrict__ agg)
{
  __shared__ float4 cs[VV];            // 64 KB
  __shared__ uint2 lists[8][CAP];      // 14336 B
  __shared__ unsigned short pr[257];   // 514 B  (total 80386 B -> 2 blk/CU)

  const int t = threadIdx.x, lane = t & 63;
  const int wvid = __builtin_amdgcn_readfirstlane(t) >> 6;
  const int bid0 = blockIdx.x;
  const int bid = (bid0 & 7) * 64 + (bid0 >> 3);   // XCD-bijective swizzle
  const int ev = bid >> 6;
  const int slot = bid & 63;
  const int evbase = ev * VV;

  {
    const float4* cg = (const float4*)coords + evbase;
    for (int i = t; i < VV; i += 512) cs[i] = cg[i];
    if (t < 257) pr[t] = prefg[ev * 257 + t];
  }
  __syncthreads();

  uint2* list = lists[wvid];
  const float* fe = feat + (size_t)evbase * 64;
  const unsigned long long lmask = (1ull << lane) - 1ull;

  // Windowed radius scan + stream compaction (indices are SORTED-space).
  auto scan = [&](unsigned rbits, int q, float4 qc, int lo, int hi) -> int {
    int M = 0;
    #pragma unroll 2
    for (int base = lo; base < hi; base += 64) {
      const int c = base + lane;
      bool pred = false;
      float dsq = 0.f;
      if (c < hi) {
        const float4 cc = cs[c];
        const float dx = qc.x - cc.x, dy = qc.y - cc.y;
        const float dz = qc.z - cc.z, dw = qc.w - cc.w;
        dsq = dx * dx + dy * dy + dz * dz + dw * dw;
        pred = (__float_as_uint(dsq) <= rbits) && (c != q);
      }
      const unsigned long long bm = __ballot(pred);
      if (pred) {
        const int pos = M + (int)__popcll(bm & lmask);
        if (pos < CAP)
          list[pos] = make_uint2(__float_as_uint(dsq), (unsigned)c);
      }
      M += (int)__popcll(bm);
    }
    return M;
  };

  for (int qi = 0; qi < 8; ++qi) {
    // Strided sorted-query assignment: every block gets a balanced mix of
    // window widths (central vs edge queries).
    const int q = slot + (wvid * 8 + qi) * 64;   // sorted-space id
    const float4 qc = cs[q];
    const int origq = (int)perm[evbase + q];     // original local id
    const int bq = xbucket(qc.x);
    const int wlo = pr[bq > 32 ? bq - 32 : 0];
    const int whi = pr[bq + 33 > 256 ? 256 : bq + 33];

    int M = scan(ONEB, q, qc, wlo, whi);
    bool ok = true;

    if (M > CAP) {
      // Refine: tau_sub = 40th smallest of the CAP stored entries (a
      // subsample => tau_sub >= true tau); re-scan at tau_sub.
      const unsigned t0 = bs40<4>(list, CAP, lane);
      M = scan(t0, q, qc, wlo, whi);
      ok = (M <= CAP);
    }

    float vmax = -__builtin_inff(), vsum = 0.f;

    if (ok) {
      // Convert stored sorted-space indices -> original local indices.
      for (int be = 0; be < M; be += 64) {
        const int e = be + lane;
        if (e < M) {
          uint2 en = list[e];
          en.y = (unsigned)perm[evbase + (int)en.y];
          list[e] = en;
        }
      }

      int Msel;
      if (M > KNN) {
        unsigned taub;
        if      (M <=  64) taub = bs40<1>(list, M, lane);
        else if (M <= 128) taub = bs40<2>(list, M, lane);
        else               taub = bs40<4>(list, M, lane);
        int S = 0;
        for (int be = 0; be < M; be += 64) {
          const int e = be + lane;
          uint2 en = make_uint2(0u, 0u);
          bool p = false;
          if (e < M) { en = list[e]; p = (en.x <= taub); }
          const unsigned long long bm = __ballot(p);
          if (p) list[S + (int)__popcll(bm & lmask)] = en;
          S += (int)__popcll(bm);
        }
        Msel = S;
      } else {
        // Pad to exactly KNN with self entries (dsq=0 -> w=1), matching the
        // reference's out-of-radius self-replacement.
        if (lane >= M && lane < KNN)
          list[lane] = make_uint2(0u, (unsigned)origq);
        Msel = KNN;
      }

      if (Msel == KNN) {
        AGG_CHUNK(0, 16)
        AGG_CHUNK(16, 16)
        AGG_CHUNK(32, 8)
      } else {
        #pragma unroll 4
        for (int e = 0; e < Msel; ++e) {
          const uint2 en = list[e];
          const int ei = __builtin_amdgcn_readfirstlane((int)en.y);
          const float w = __expf(-10.f * __uint_as_float(en.x));
          const float v = fe[(size_t)ei * 64 + lane] * w;
          vmax = fmaxf(vmax, v);
          vsum += v;
        }
      }
    } else {
      // Exact fallback within the window (statistically unreachable).
      unsigned lo = 0, hi = ONEB;
      while (lo < hi) {
        const unsigned mid = (lo + hi) >> 1;
        const float fm = __uint_as_float(mid);
        int cnt = 0;
        for (int base = wlo; base < whi; base += 64) {
          const int c = base + lane;
          bool p = false;
          if (c < whi) {
            const float4 cc = cs[c];
            const float dx = qc.x - cc.x, dy = qc.y - cc.y;
            const float dz = qc.z - cc.z, dw = qc.w - cc.w;
            const float dsq = dx * dx + dy * dy + dz * dz + dw * dw;
            p = (dsq <= fm && c != q);
          }
          cnt += (int)__popcll(__ballot(p));
        }
        if (cnt >= KNN) hi = mid; else lo = mid + 1;
      }
      const float tau = __uint_as_float(hi);
      for (int c = wlo; c < whi; ++c) {
        if (c == q) continue;
        const float4 cc = cs[c];
        const float dx = qc.x - cc.x, dy = qc.y - cc.y;
        const float dz = qc.z - cc.z, dw = qc.w - cc.w;
        const float dsq = dx * dx + dy * dy + dz * dz + dw * dw;
        if (dsq <= tau) {
          const int ei = (int)perm[evbase + c];
          const float w = __expf(-10.f * dsq);
          const float v = fe[(size_t)ei * 64 + lane] * w;
          vmax = fmaxf(vmax, v);
          vsum += v;
        }
      }
    }

    const int g = evbase + origq;
    agg[(size_t)g * 128 + lane]      = vmax;
    agg[(size_t)g * 128 + 64 + lane] = vsum * (1.f / 40.f);
  }
}

// ---------------------------------------------------------------------------
// Kernel 3: out = tanh(agg @ W_out[0:128,:] + xW + b_out), in place on d_out
// ---------------------------------------------------------------------------
__global__ __launch_bounds__(256) void k_out(
    const float* __restrict__ agg, const float* __restrict__ W_out,
    const float* __restrict__ b_out, float* __restrict__ out)
{
  __shared__ float at[64][128];
  const int t = threadIdx.x;
  const int row0 = blockIdx.x * 64;

  #pragma unroll
  for (int i = 0; i < 32; ++i) {
    int idx = t + i * 256;
    at[idx >> 7][idx & 127] = agg[(size_t)row0 * 128 + idx];
  }
  __syncthreads();

  const int col = t & 127, who = t >> 7;
  #pragma unroll
  for (int p = 0; p < 2; ++p) {
    const int rb = who * 16 + p * 32;
    float acc[16];
    #pragma unroll
    for (int i = 0; i < 16; ++i) acc[i] = 0.f;
    for (int k = 0; k < 128; k += 4) {
      const float w0 = W_out[(size_t)(k + 0) * 128 + col];
      const float w1 = W_out[(size_t)(k + 1) * 128 + col];
      const float w2 = W_out[(size_t)(k + 2) * 128 + col];
      const float w3 = W_out[(size_t)(k + 3) * 128 + col];
      #pragma unroll
      for (int i = 0; i < 16; ++i) {
        const float4 a4 = *(const float4*)&at[rb + i][k];
        acc[i] += a4.x * w0 + a4.y * w1 + a4.z * w2 + a4.w * w3;
      }
    }
    const float bb = b_out[col];
    #pragma unroll
    for (int i = 0; i < 16; ++i) {
      const size_t o = (size_t)(row0 + rb + i) * 128 + col;
      float v = acc[i] + bb + out[o];   // out currently holds xW
      v = fminf(15.f, fmaxf(-15.f, v));
      const float e = __expf(2.f * v);
      out[o] = (e - 1.f) / (e + 1.f);
    }
  }
}

// ---------------------------------------------------------------------------
extern "C" void kernel_launch(void* const* d_in, const int* in_sizes, int n_in,
                              void* d_out, int out_size, void* d_ws, size_t ws_size,
                              hipStream_t stream) {
  const float* x      = (const float*)d_in[0];
  const float* W_prop = (const float*)d_in[1];
  const float* b_prop = (const float*)d_in[2];
  const float* W_sp   = (const float*)d_in[3];
  const float* b_sp   = (const float*)d_in[4];
  const float* W_out  = (const float*)d_in[5];
  const float* b_out  = (const float*)d_in[6];

  float* out = (float*)d_out;
  char* ws = (char*)d_ws;
  float* coords          = (float*)ws;                              // 512 KB
  float* feat            = (float*)(ws + (512 << 10));              // 8 MB
  float* agg             = (float*)(ws + (512 << 10) + (8 << 20));  // 16 MB
  unsigned short* perm   = (unsigned short*)(ws + (512 << 10) + (24 << 20)); // 64 KB
  unsigned short* prefg  = (unsigned short*)(ws + (512 << 10) + (24 << 20) + (64 << 10)); // ~4 KB
  // total ws use: ~24.57 MB

  k_prep<<<NTOT / 64, 256, 0, stream>>>(x, W_prop, b_prop, W_sp, b_sp, W_out,
                                        coords, feat, out /* xW staged here */);
  k_sort<<<NB, 512, 0, stream>>>(coords, perm, prefg);
  k_knn<<<NB * (VV / 64), 512, 0, stream>>>(coords, perm, prefg, feat, agg);
  k_out<<<NTOT / 64, 256, 0, stream>>>(agg, W_out, b_out, out);
}

// Round 10
// 177.160 us; speedup vs baseline: 1.1960x; 1.1960x over previous
//
#include <hip/hip_runtime.h>
#include <cstdint>
#include <cstddef>

// Problem constants (fixed by the reference file)
#define NB   8
#define VV   4096
#define KNN  40
#define NTOT 32768
#define CAP  224   // compact within-radius list capacity per query
#define INFB 0x7F800000u
#define ONEB 0x3F800000u

__device__ __forceinline__ int xbucket(float x) {
  int b = (int)floorf((x + 4.f) * 32.f);
  return b < 0 ? 0 : (b > 255 ? 255 : b);
}

// ---------------------------------------------------------------------------
// Kernel 1: coords = x@W_sp + b_sp ; feat = x@W_prop + b_prop ;
//           xW = x @ W_out[128:192,:]  (written into d_out, fused later)
// ---------------------------------------------------------------------------
__global__ __launch_bounds__(256) void k_prep(
    const float* __restrict__ x, const float* __restrict__ W_prop,
    const float* __restrict__ b_prop, const float* __restrict__ W_sp,
    const float* __restrict__ b_sp, const float* __restrict__ W_out,
    float* __restrict__ coords, float* __restrict__ feat,
    float* __restrict__ xW)
{
  __shared__ float xt[64][64];
  const int t = threadIdx.x;
  const int row0 = blockIdx.x * 64;

  #pragma unroll
  for (int i = 0; i < 16; ++i) {
    int idx = t + i * 256;
    xt[idx >> 6][idx & 63] = x[(size_t)row0 * 64 + idx];
  }
  __syncthreads();

  {
    const int col = t & 63, rb = (t >> 6) * 16;
    float acc[16];
    #pragma unroll
    for (int i = 0; i < 16; ++i) acc[i] = b_prop[col];
    for (int k = 0; k < 64; k += 4) {
      const float w0 = W_prop[(k + 0) * 64 + col];
      const float w1 = W_prop[(k + 1) * 64 + col];
      const float w2 = W_prop[(k + 2) * 64 + col];
      const float w3 = W_prop[(k + 3) * 64 + col];
      #pragma unroll
      for (int i = 0; i < 16; ++i) {
        const float4 a4 = *(const float4*)&xt[rb + i][k];
        acc[i] += a4.x * w0 + a4.y * w1 + a4.z * w2 + a4.w * w3;
      }
    }
    #pragma unroll
    for (int i = 0; i < 16; ++i)
      feat[(size_t)(row0 + rb + i) * 64 + col] = acc[i];
  }

  {
    const int col = t & 127, who = t >> 7;
    #pragma unroll
    for (int p = 0; p < 2; ++p) {
      const int rb = who * 16 + p * 32;
      float acc[16];
      #pragma unroll
      for (int i = 0; i < 16; ++i) acc[i] = 0.f;
      for (int k = 0; k < 64; k += 4) {
        const float w0 = W_out[(size_t)(128 + k + 0) * 128 + col];
        const float w1 = W_out[(size_t)(128 + k + 1) * 128 + col];
        const float w2 = W_out[(size_t)(128 + k + 2) * 128 + col];
        const float w3 = W_out[(size_t)(128 + k + 3) * 128 + col];
        #pragma unroll
        for (int i = 0; i < 16; ++i) {
          const float4 a4 = *(const float4*)&xt[rb + i][k];
          acc[i] += a4.x * w0 + a4.y * w1 + a4.z * w2 + a4.w * w3;
        }
      }
      #pragma unroll
      for (int i = 0; i < 16; ++i)
        xW[(size_t)(row0 + rb + i) * 128 + col] = acc[i];
    }
  }

  if (t < 64) {
    float a0 = b_sp[0], a1 = b_sp[1], a2 = b_sp[2], a3 = b_sp[3];
    for (int k = 0; k < 64; ++k) {
      const float xv = xt[t][k];
      a0 += xv * W_sp[k * 4 + 0];
      a1 += xv * W_sp[k * 4 + 1];
      a2 += xv * W_sp[k * 4 + 2];
      a3 += xv * W_sp[k * 4 + 3];
    }
    ((float4*)coords)[row0 + t] = make_float4(a0, a1, a2, a3);
  }
}

// ---------------------------------------------------------------------------
// Kernel 1b: per-event counting sort of coords by x (in place), 256 buckets.
// Emits perm (sorted pos -> original local idx, u16) and bucket prefix (u16).
// ---------------------------------------------------------------------------
__global__ __launch_bounds__(512) void k_sort(
    float* __restrict__ coords, unsigned short* __restrict__ perm,
    unsigned short* __restrict__ prefg)
{
  __shared__ float4 cs[VV];      // 64 KB staging (makes in-place safe)
  __shared__ int hist[256];
  __shared__ int pref[257];
  const int t = threadIdx.x, ev = blockIdx.x;
  const int evbase = ev * VV;
  float4* cg = (float4*)coords + evbase;

  for (int i = t; i < VV; i += 512) cs[i] = cg[i];
  if (t < 256) hist[t] = 0;
  __syncthreads();

  for (int i = t; i < VV; i += 512)
    atomicAdd(&hist[xbucket(cs[i].x)], 1);
  __syncthreads();

  if (t < 64) {
    const int l = t;
    const int h0 = hist[4*l], h1 = hist[4*l+1], h2 = hist[4*l+2], h3 = hist[4*l+3];
    const int s = h0 + h1 + h2 + h3;
    int incl = s;
    #pragma unroll
    for (int off = 1; off < 64; off <<= 1) {
      const int v = __shfl_up(incl, off);
      if (l >= off) incl += v;
    }
    const int excl = incl - s;
    pref[4*l]   = excl;
    pref[4*l+1] = excl + h0;
    pref[4*l+2] = excl + h0 + h1;
    pref[4*l+3] = excl + h0 + h1 + h2;
    if (l == 63) pref[256] = excl + s;   // == VV
  }
  __syncthreads();
  if (t < 256) hist[t] = 0;              // reuse as scatter counters
  __syncthreads();

  for (int i = t; i < VV; i += 512) {
    const int b = xbucket(cs[i].x);
    const int pos = pref[b] + atomicAdd(&hist[b], 1);
    cg[pos] = cs[i];
    perm[evbase + pos] = (unsigned short)i;
  }
  if (t < 257) prefg[ev * 257 + t] = (unsigned short)pref[t];
}

// ---------------------------------------------------------------------------
// Kernel 2: per-query KNN + aggregation on SORTED coords with 64-ALIGNED
// bucket-window prune (no per-element bounds check, full unroll).
// ---------------------------------------------------------------------------
template <int NC>
__device__ __forceinline__ unsigned bs40(const uint2* __restrict__ list,
                                         int M, int lane) {
  unsigned dv[NC];
  #pragma unroll
  for (int j = 0; j < NC; ++j) {
    const int e = lane + j * 64;
    dv[j] = (e < M) ? list[e].x : INFB;
  }
  unsigned lo = 0, hi = ONEB;
  while (lo < hi) {
    const unsigned mid = (lo + hi) >> 1;
    int cnt = 0;
    #pragma unroll
    for (int j = 0; j < NC; ++j)
      cnt += (int)__popcll(__ballot(dv[j] <= mid));
    if (cnt >= KNN) hi = mid; else lo = mid + 1;
  }
  return hi;
}

#define AGG_CHUNK(J0, N)                                                     \
  {                                                                          \
    float fv[N], wgt[N];                                                     \
    _Pragma("unroll")                                                        \
    for (int j = 0; j < N; ++j) {                                            \
      const uint2 en = list[(J0) + j];                                       \
      wgt[j] = __expf(-10.f * __uint_as_float(en.x));                        \
      const int ei = __builtin_amdgcn_readfirstlane((int)en.y);              \
      fv[j] = fe[(size_t)ei * 64 + lane];                                    \
    }                                                                        \
    _Pragma("unroll")                                                        \
    for (int j = 0; j < N; ++j) {                                            \
      const float v = fv[j] * wgt[j];                                        \
      vmax = fmaxf(vmax, v);                                                 \
      vsum += v;                                                             \
    }                                                                        \
  }

__global__ __launch_bounds__(512, 4) void k_knn(
    const float* __restrict__ coords,           // sorted by x per event
    const unsigned short* __restrict__ perm,    // sorted pos -> orig local
    const unsigned short* __restrict__ prefg,
    const float* __restrict__ feat, float* __restrict__ agg)
{
  __shared__ float4 cs[VV];            // 64 KB
  __shared__ uint2 lists[8][CAP];      // 14336 B
  __shared__ unsigned short pr[257];   // 514 B  (total ~80 KB -> 2 blk/CU)

  const int t = threadIdx.x, lane = t & 63;
  const int wvid = __builtin_amdgcn_readfirstlane(t) >> 6;
  const int bid0 = blockIdx.x;
  const int bid = (bid0 & 7) * 64 + (bid0 >> 3);   // XCD-bijective swizzle
  const int ev = bid >> 6;
  const int slot = bid & 63;
  const int evbase = ev * VV;

  {
    const float4* cg = (const float4*)coords + evbase;
    for (int i = t; i < VV; i += 512) cs[i] = cg[i];
    if (t < 257) pr[t] = prefg[ev * 257 + t];
  }
  __syncthreads();

  uint2* list = lists[wvid];
  const float* fe = feat + (size_t)evbase * 64;
  const unsigned long long lmask = (1ull << lane) - 1ull;

  // Windowed radius scan, 64-aligned bounds: no per-element check, aligned
  // ds_read_b128, unroll 4. Extra candidates outside the true bucket window
  // have |dx|>1 -> fail the radius predicate -> M and results unchanged.
  auto scan = [&](unsigned rbits, int q, float4 qc, int lo, int hi) -> int {
    int M = 0;
    #pragma unroll 4
    for (int base = lo; base < hi; base += 64) {
      const int c = base + lane;
      const float4 cc = cs[c];
      const float dx = qc.x - cc.x, dy = qc.y - cc.y;
      const float dz = qc.z - cc.z, dw = qc.w - cc.w;
      const float dsq = dx * dx + dy * dy + dz * dz + dw * dw;
      const bool pred = (__float_as_uint(dsq) <= rbits) && (c != q);
      const unsigned long long bm = __ballot(pred);
      if (pred) {
        const int pos = M + (int)__popcll(bm & lmask);
        if (pos < CAP)
          list[pos] = make_uint2(__float_as_uint(dsq), (unsigned)c);
      }
      M += (int)__popcll(bm);
    }
    return M;
  };

  for (int qi = 0; qi < 8; ++qi) {
    // Transposed strided assignment: each WAVE draws one query from each
    // 512-band of sorted order -> per-wave window-width balance.
    const int q = slot + (qi * 8 + wvid) * 64;   // sorted-space id
    const float4 qc = cs[q];
    const int origq = (int)perm[evbase + q];     // original local id
    const int bq = xbucket(qc.x);
    const int wlo = ((int)pr[bq > 32 ? bq - 32 : 0]) & ~63;
    const int whi0 = (int)pr[bq + 33 > 256 ? 256 : bq + 33];
    const int whi = (whi0 + 63) & ~63;           // <= VV (VV is 64-aligned)

    int M = scan(ONEB, q, qc, wlo, whi);
    bool ok = true;

    if (M > CAP) {
      // Refine: tau_sub = 40th smallest of the CAP stored entries (a
      // subsample => tau_sub >= true tau); re-scan at tau_sub.
      const unsigned t0 = bs40<4>(list, CAP, lane);
      M = scan(t0, q, qc, wlo, whi);
      ok = (M <= CAP);
    }

    float vmax = -__builtin_inff(), vsum = 0.f;

    if (ok) {
      // Convert stored sorted-space indices -> original local indices.
      for (int be = 0; be < M; be += 64) {
        const int e = be + lane;
        if (e < M) {
          uint2 en = list[e];
          en.y = (unsigned)perm[evbase + (int)en.y];
          list[e] = en;
        }
      }

      int Msel;
      if (M > KNN) {
        unsigned taub;
        if      (M <=  64) taub = bs40<1>(list, M, lane);
        else if (M <= 128) taub = bs40<2>(list, M, lane);
        else               taub = bs40<4>(list, M, lane);
        int S = 0;
        for (int be = 0; be < M; be += 64) {
          const int e = be + lane;
          uint2 en = make_uint2(0u, 0u);
          bool p = false;
          if (e < M) { en = list[e]; p = (en.x <= taub); }
          const unsigned long long bm = __ballot(p);
          if (p) list[S + (int)__popcll(bm & lmask)] = en;
          S += (int)__popcll(bm);
        }
        Msel = S;
      } else {
        // Pad to exactly KNN with self entries (dsq=0 -> w=1), matching the
        // reference's out-of-radius self-replacement.
        if (lane >= M && lane < KNN)
          list[lane] = make_uint2(0u, (unsigned)origq);
        Msel = KNN;
      }

      if (Msel == KNN) {
        AGG_CHUNK(0, 16)
        AGG_CHUNK(16, 16)
        AGG_CHUNK(32, 8)
      } else {
        #pragma unroll 4
        for (int e = 0; e < Msel; ++e) {
          const uint2 en = list[e];
          const int ei = __builtin_amdgcn_readfirstlane((int)en.y);
          const float w = __expf(-10.f * __uint_as_float(en.x));
          const float v = fe[(size_t)ei * 64 + lane] * w;
          vmax = fmaxf(vmax, v);
          vsum += v;
        }
      }
    } else {
      // Exact fallback within the aligned window (statistically unreachable).
      unsigned lo = 0, hi = ONEB;
      while (lo < hi) {
        const unsigned mid = (lo + hi) >> 1;
        const float fm = __uint_as_float(mid);
        int cnt = 0;
        for (int base = wlo; base < whi; base += 64) {
          const int c = base + lane;
          const float4 cc = cs[c];
          const float dx = qc.x - cc.x, dy = qc.y - cc.y;
          const float dz = qc.z - cc.z, dw = qc.w - cc.w;
          const float dsq = dx * dx + dy * dy + dz * dz + dw * dw;
          cnt += (int)__popcll(__ballot(dsq <= fm && c != q));
        }
        if (cnt >= KNN) hi = mid; else lo = mid + 1;
      }
      const float tau = __uint_as_float(hi);
      for (int c = wlo; c < whi; ++c) {
        if (c == q) continue;
        const float4 cc = cs[c];
        const float dx = qc.x - cc.x, dy = qc.y - cc.y;
        const float dz = qc.z - cc.z, dw = qc.w - cc.w;
        const float dsq = dx * dx + dy * dy + dz * dz + dw * dw;
        if (dsq <= tau) {
          const int ei = (int)perm[evbase + c];
          const float w = __expf(-10.f * dsq);
          const float v = fe[(size_t)ei * 64 + lane] * w;
          vmax = fmaxf(vmax, v);
          vsum += v;
        }
      }
    }

    const int g = evbase + origq;
    agg[(size_t)g * 128 + lane]      = vmax;
    agg[(size_t)g * 128 + 64 + lane] = vsum * (1.f / 40.f);
  }
}

// ---------------------------------------------------------------------------
// Kernel 3: out = tanh(agg @ W_out[0:128,:] + xW + b_out), in place on d_out
// ---------------------------------------------------------------------------
__global__ __launch_bounds__(256) void k_out(
    const float* __restrict__ agg, const float* __restrict__ W_out,
    const float* __restrict__ b_out, float* __restrict__ out)
{
  __shared__ float at[64][128];
  const int t = threadIdx.x;
  const int row0 = blockIdx.x * 64;

  #pragma unroll
  for (int i = 0; i < 32; ++i) {
    int idx = t + i * 256;
    at[idx >> 7][idx & 127] = agg[(size_t)row0 * 128 + idx];
  }
  __syncthreads();

  const int col = t & 127, who = t >> 7;
  #pragma unroll
  for (int p = 0; p < 2; ++p) {
    const int rb = who * 16 + p * 32;
    float acc[16];
    #pragma unroll
    for (int i = 0; i < 16; ++i) acc[i] = 0.f;
    for (int k = 0; k < 128; k += 4) {
      const float w0 = W_out[(size_t)(k + 0) * 128 + col];
      const float w1 = W_out[(size_t)(k + 1) * 128 + col];
      const float w2 = W_out[(size_t)(k + 2) * 128 + col];
      const float w3 = W_out[(size_t)(k + 3) * 128 + col];
      #pragma unroll
      for (int i = 0; i < 16; ++i) {
        const float4 a4 = *(const float4*)&at[rb + i][k];
        acc[i] += a4.x * w0 + a4.y * w1 + a4.z * w2 + a4.w * w3;
      }
    }
    const float bb = b_out[col];
    #pragma unroll
    for (int i = 0; i < 16; ++i) {
      const size_t o = (size_t)(row0 + rb + i) * 128 + col;
      float v = acc[i] + bb + out[o];   // out currently holds xW
      v = fminf(15.f, fmaxf(-15.f, v));
      const float e = __expf(2.f * v);
      out[o] = (e - 1.f) / (e + 1.f);
    }
  }
}

// ---------------------------------------------------------------------------
extern "C" void kernel_launch(void* const* d_in, const int* in_sizes, int n_in,
                              void* d_out, int out_size, void* d_ws, size_t ws_size,
                              hipStream_t stream) {
  const float* x      = (const float*)d_in[0];
  const float* W_prop = (const float*)d_in[1];
  const float* b_prop = (const float*)d_in[2];
  const float* W_sp   = (const float*)d_in[3];
  const float* b_sp   = (const float*)d_in[4];
  const float* W_out  = (const float*)d_in[5];
  const float* b_out  = (const float*)d_in[6];

  float* out = (float*)d_out;
  char* ws = (char*)d_ws;
  float* coords          = (float*)ws;                              // 512 KB
  float* feat            = (float*)(ws + (512 << 10));              // 8 MB
  float* agg             = (float*)(ws + (512 << 10) + (8 << 20));  // 16 MB
  unsigned short* perm   = (unsigned short*)(ws + (512 << 10) + (24 << 20)); // 64 KB
  unsigned short* prefg  = (unsigned short*)(ws + (512 << 10) + (24 << 20) + (64 << 10)); // ~4 KB

  k_prep<<<NTOT / 64, 256, 0, stream>>>(x, W_prop, b_prop, W_sp, b_sp, W_out,
                                        coords, feat, out /* xW staged here */);
  k_sort<<<NB, 512, 0, stream>>>(coords, perm, prefg);
  k_knn<<<NB * (VV / 64), 512, 0, stream>>>(coords, perm, prefg, feat, agg);
  k_out<<<NTOT / 64, 256, 0, stream>>>(agg, W_out, b_out, out);
}